// Round 13
// baseline (862.619 us; speedup 1.0000x reference)
//
#include <hip/hip_runtime.h>
#include <hip/hip_bf16.h>
#include <math.h>

// Problem constants
#define DEPTH 4
#define DIM 384
#define HEADS 8
#define DHEAD 64
#define INNER 512
#define HID 96
#define BATCH 8
#define NTOK 1024          // 32*32
#define ROWS (BATCH*NTOK)  // 8192

typedef __attribute__((ext_vector_type(8))) _Float16 half8;
typedef __attribute__((ext_vector_type(4))) _Float16 half4;
typedef __attribute__((ext_vector_type(2))) _Float16 half2v;
typedef __attribute__((ext_vector_type(4))) float f32x4;

// F-layout (fragment-native): elem (r,k) at ((r>>4)*KS+(k>>5))*512+(r&15)*32+(k&31)

// ---------------------------------------------------------------------------
// fp32 -> fp16 convert (initial residual stream). grid-stride over float4.
// ---------------------------------------------------------------------------
__global__ __launch_bounds__(256) void cvt_kernel(const float* __restrict__ in,
                                                  _Float16* __restrict__ out) {
  const int i = blockIdx.x * 256 + threadIdx.x;  // n4 = ROWS*DIM/4
  if (i < ROWS * DIM / 4) {
    const float4 v = ((const float4*)in)[i];
    half4 o = {(_Float16)v.x, (_Float16)v.y, (_Float16)v.z, (_Float16)v.w};
    *(half4*)(out + (size_t)i * 4) = o;
  }
}

// ---------------------------------------------------------------------------
// LayerNorm over last dim (384), fp16 in -> fp16 F-layout out. One wave/row.
// ---------------------------------------------------------------------------
__global__ __launch_bounds__(256) void ln_kernel(const _Float16* __restrict__ x,
                                                 const float* __restrict__ w,
                                                 const float* __restrict__ b,
                                                 _Float16* __restrict__ outF) {
  const int row = blockIdx.x * 4 + (threadIdx.x >> 6);
  const int lane = threadIdx.x & 63;
  const _Float16* xr = x + (size_t)row * DIM;
  float v[6];
  float s = 0.f;
#pragma unroll
  for (int i = 0; i < 3; ++i) {
    half2v h = *(const half2v*)(xr + i * 128 + lane * 2);
    v[2 * i] = (float)h[0];
    v[2 * i + 1] = (float)h[1];
    s += v[2 * i] + v[2 * i + 1];
  }
#pragma unroll
  for (int m = 1; m < 64; m <<= 1) s += __shfl_xor(s, m);
  const float mean = s * (1.0f / DIM);
  float sq = 0.f;
#pragma unroll
  for (int i = 0; i < 6; ++i) {
    v[i] -= mean;
    sq += v[i] * v[i];
  }
#pragma unroll
  for (int m = 1; m < 64; m <<= 1) sq += __shfl_xor(sq, m);
  const float rs = rsqrtf(sq * (1.0f / DIM) + 1e-5f);
  const int f = row >> 4, lr = row & 15;
#pragma unroll
  for (int i = 0; i < 3; ++i) {
#pragma unroll
    for (int j = 0; j < 2; ++j) {
      const int k = i * 128 + lane * 2 + j;
      outF[(((size_t)f * 12 + (k >> 5)) * 16 + lr) * 32 + (k & 31)] =
          (_Float16)(v[2 * i + j] * rs * w[k] + b[k]);
    }
  }
}

// ---------------------------------------------------------------------------
// Weight transpose+convert to F-layout: fp32 [K][N] -> fp16 F over (Npad, K).
// ---------------------------------------------------------------------------
__global__ __launch_bounds__(256) void transposeW(const float* __restrict__ in0,
                                                  _Float16* __restrict__ out0,
                                                  int K, int N, int Npad) {
  __shared__ float t[32][33];
  const int l = blockIdx.z;
  const int KS = K >> 5;
  const float* in = in0 + (size_t)l * K * N;
  _Float16* out = out0 + (size_t)l * Npad * K;
  const int k0 = blockIdx.x * 32, n0 = blockIdx.y * 32;
  const int tx = threadIdx.x & 31, ty = threadIdx.x >> 5;
#pragma unroll
  for (int i = 0; i < 4; ++i) {
    int k = k0 + ty + i * 8, n = n0 + tx;
    t[ty + i * 8][tx] = (n < N) ? in[(size_t)k * N + n] : 0.f;
  }
  __syncthreads();
  const int k = k0 + tx;
#pragma unroll
  for (int i = 0; i < 4; ++i) {
    int n = n0 + ty + i * 8;
    if (n < Npad)
      out[(((size_t)(n >> 4) * KS + (k >> 5)) * 16 + (n & 15)) * 32 + (k & 31)] =
          (_Float16)t[tx][ty + i * 8];
  }
}

// ---------------------------------------------------------------------------
// fp16 MFMA GEMM, F-layout A/B: C = A @ B^T (+bias, +fp16 residual).
// 128x128 tile, 4 waves (2x2), 64x64/wave. OUT16: fp16 out, else fp32.
// ---------------------------------------------------------------------------
template <bool BIAS, bool RES, bool OUT16, int KT, int NT>
__global__ __launch_bounds__(256) void hgemm(const _Float16* __restrict__ AF,
                                             const _Float16* __restrict__ BF,
                                             const float* __restrict__ bias,
                                             const _Float16* __restrict__ res,
                                             void* __restrict__ Cout) {
  constexpr int KS = KT / 32;
  const int tid = threadIdx.x;
  const int wave = tid >> 6, lane = tid & 63;
  const int wm = wave >> 1, wn = wave & 1;
  const int g = lane >> 4, lr = lane & 15;
  const int m0 = blockIdx.x * 128 + wm * 64;
  const int n0 = blockIdx.y * 128 + wn * 64;
  const int fA = m0 >> 4, fB = n0 >> 4;
  const int lo = lr * 32 + g * 8;
  f32x4 acc[4][4];
#pragma unroll
  for (int i = 0; i < 4; ++i)
#pragma unroll
    for (int j = 0; j < 4; ++j) acc[i][j] = {0.f, 0.f, 0.f, 0.f};

  for (int ks = 0; ks < KS; ++ks) {
    half8 af[4], bf[4];
#pragma unroll
    for (int i = 0; i < 4; ++i)
      af[i] = *(const half8*)(AF + ((size_t)(fA + i) * KS + ks) * 512 + lo);
#pragma unroll
    for (int j = 0; j < 4; ++j)
      bf[j] = *(const half8*)(BF + ((size_t)(fB + j) * KS + ks) * 512 + lo);
#pragma unroll
    for (int i = 0; i < 4; ++i)
#pragma unroll
      for (int j = 0; j < 4; ++j)
        acc[i][j] =
            __builtin_amdgcn_mfma_f32_16x16x32_f16(af[i], bf[j], acc[i][j], 0, 0, 0);
  }

#pragma unroll
  for (int i = 0; i < 4; ++i) {
#pragma unroll
    for (int j = 0; j < 4; ++j) {
      const int n = n0 + j * 16 + lr;
      if (NT % 128 == 0 || n < NT) {
        float bb = BIAS ? bias[n] : 0.f;
#pragma unroll
        for (int jj = 0; jj < 4; ++jj) {
          const int m = m0 + i * 16 + g * 4 + jj;
          float v = acc[i][j][jj] + bb;
          const size_t idx = (size_t)m * NT + n;
          if (RES) v += (float)res[idx];
          if (OUT16)
            ((_Float16*)Cout)[idx] = (_Float16)v;
          else
            ((float*)Cout)[idx] = v;
        }
      }
    }
  }
}

// ---------------------------------------------------------------------------
// fc1 GEMM: 32x128 tile, F-layout A/B; C fp16 row-major [8192][96]. grid 256.
// ---------------------------------------------------------------------------
__global__ __launch_bounds__(256) void hgemm_fc1(const _Float16* __restrict__ AF,
                                                 const _Float16* __restrict__ BF,
                                                 const float* __restrict__ bias,
                                                 _Float16* __restrict__ C) {
  const int tid = threadIdx.x;
  const int wave = tid >> 6, lane = tid & 63;
  const int g = lane >> 4, lr = lane & 15;
  const int m0 = blockIdx.x * 32;
  const int fA = m0 >> 4, fB = wave * 2;
  const int lo = lr * 32 + g * 8;
  f32x4 acc[2][2];
#pragma unroll
  for (int i = 0; i < 2; ++i)
#pragma unroll
    for (int j = 0; j < 2; ++j) acc[i][j] = {0.f, 0.f, 0.f, 0.f};

  for (int ks = 0; ks < 12; ++ks) {
    half8 af[2], bf[2];
#pragma unroll
    for (int i = 0; i < 2; ++i)
      af[i] = *(const half8*)(AF + ((size_t)(fA + i) * 12 + ks) * 512 + lo);
#pragma unroll
    for (int j = 0; j < 2; ++j)
      bf[j] = *(const half8*)(BF + ((size_t)(fB + j) * 12 + ks) * 512 + lo);
#pragma unroll
    for (int i = 0; i < 2; ++i)
#pragma unroll
      for (int j = 0; j < 2; ++j)
        acc[i][j] =
            __builtin_amdgcn_mfma_f32_16x16x32_f16(af[i], bf[j], acc[i][j], 0, 0, 0);
  }

#pragma unroll
  for (int i = 0; i < 2; ++i)
#pragma unroll
    for (int j = 0; j < 2; ++j) {
      const int n = wave * 32 + j * 16 + lr;
      if (n < HID) {
        const float bb = bias[n];
#pragma unroll
        for (int jj = 0; jj < 4; ++jj) {
          const int m = m0 + i * 16 + g * 4 + jj;
          C[(size_t)m * HID + n] = (_Float16)(acc[i][j][jj] + bb);
        }
      }
    }
}

// ---------------------------------------------------------------------------
// qkv GEMM (F-layout A/B). Epilogue emits qF (F-layout), kT, vTn.
// ---------------------------------------------------------------------------
__global__ __launch_bounds__(256) void hgemm_qkv(const _Float16* __restrict__ AF,
                                                 const _Float16* __restrict__ BF,
                                                 _Float16* __restrict__ qF,
                                                 _Float16* __restrict__ kT,
                                                 _Float16* __restrict__ vTn) {
  const int tid = threadIdx.x;
  const int wave = tid >> 6, lane = tid & 63;
  const int wm = wave >> 1, wn = wave & 1;
  const int g = lane >> 4, lr = lane & 15;
  const int m0 = blockIdx.x * 128 + wm * 64;
  const int n0 = blockIdx.y * 128 + wn * 64;
  const int fA = m0 >> 4, fB = n0 >> 4;
  const int lo = lr * 32 + g * 8;
  f32x4 acc[4][4];
#pragma unroll
  for (int i = 0; i < 4; ++i)
#pragma unroll
    for (int j = 0; j < 4; ++j) acc[i][j] = {0.f, 0.f, 0.f, 0.f};

  for (int ks = 0; ks < 12; ++ks) {
    half8 af[4], bf[4];
#pragma unroll
    for (int i = 0; i < 4; ++i)
      af[i] = *(const half8*)(AF + ((size_t)(fA + i) * 12 + ks) * 512 + lo);
#pragma unroll
    for (int j = 0; j < 4; ++j)
      bf[j] = *(const half8*)(BF + ((size_t)(fB + j) * 12 + ks) * 512 + lo);
#pragma unroll
    for (int i = 0; i < 4; ++i)
#pragma unroll
      for (int j = 0; j < 4; ++j)
        acc[i][j] =
            __builtin_amdgcn_mfma_f32_16x16x32_f16(af[i], bf[j], acc[i][j], 0, 0, 0);
  }

  if (n0 < 512) {
#pragma unroll
    for (int i = 0; i < 4; ++i)
#pragma unroll
      for (int j = 0; j < 4; ++j) {
        const int n = n0 + j * 16 + lr;
#pragma unroll
        for (int jj = 0; jj < 4; ++jj) {
          const int m = m0 + i * 16 + g * 4 + jj;
          qF[(((size_t)(m >> 4) * 16 + (n >> 5)) * 16 + (m & 15)) * 32 + (n & 31)] =
              (_Float16)acc[i][j][jj];
        }
      }
  } else if (n0 < 1024) {
#pragma unroll
    for (int j = 0; j < 4; ++j) {
      const int n = n0 + j * 16 + lr;
      const int hk = (n - 512) >> 6, d = (n - 512) & 63;
      const int sb = d >> 5, dd = d & 31;
#pragma unroll
      for (int i = 0; i < 4; ++i)
#pragma unroll
        for (int jj = 0; jj < 4; ++jj) {
          const int m = m0 + i * 16 + g * 4 + jj;
          const int bb = m >> 10, tok = m & 1023;
          const int f = tok >> 4, tr = tok & 15;
          kT[((((size_t)(bb * 8 + hk) * 64 + f) * 2 + sb) * 16 + tr) * 32 + dd] =
              (_Float16)acc[i][j][jj];
        }
    }
  } else {
    const int bb = m0 >> 10;
    const int tok0 = (m0 & 1023) + g * 4;
#pragma unroll
    for (int j = 0; j < 4; ++j) {
      const int dg = n0 + j * 16 + lr - 1024;
      const int hk = dg >> 6, d = dg & 63;
#pragma unroll
      for (int i = 0; i < 4; ++i) {
        const int tok = tok0 + i * 16;
        const int kb = tok >> 5, tk = tok & 31;
        half4 t = {(_Float16)acc[i][j][0], (_Float16)acc[i][j][1],
                   (_Float16)acc[i][j][2], (_Float16)acc[i][j][3]};
        *(half4*)(vTn + (((size_t)(bb * 8 + hk) * 32 + kb) * 64 + d) * 32 + tk) = t;
      }
    }
  }
}

// ---------------------------------------------------------------------------
// MFMA fp16 attention v8: TWO row-tiles per block (grid 2048), probing the
// per-dispatch block-throughput cap. Per-tile structure = v7 (4 barriers,
// register-held prev in C-fragment-tiled astore layout).
// ---------------------------------------------------------------------------
__device__ __forceinline__ int pidx(int r, int c) {
  return ((((r << 11) + (c << 1)) ^ ((r & 15) << 4)) >> 1);
}

__global__ __launch_bounds__(512) void attn_kernel(
    const _Float16* __restrict__ qF, const _Float16* __restrict__ kT,
    const _Float16* __restrict__ vTn, _Float16* __restrict__ store,
    _Float16* __restrict__ aoutF, int has_prev, int write_store) {
  __shared__ __align__(16) char smem[32768];       // P (fp16 16x1024) ...
  _Float16* P = (_Float16*)smem;                   // ... then red aliases it
  float (*red)[16][68] = (float (*)[16][68])smem;  // red[2][16][68] = 8.7 KB
  __shared__ __align__(16) float partial[8][16];

  const int tid = threadIdx.x;
  const int wave = tid >> 6, lane = tid & 63;
  const int g = lane >> 4, lr = lane & 15;
  const int blk = blockIdx.x;
  const int xcd = blk & 7, j0 = blk >> 3;
  const int bh = xcd * 8 + (j0 >> 5);
  const int pair = j0 & 31;
  const int b = bh >> 3, h = bh & 7;

  const _Float16* kbase = kT + (size_t)bh * 64 * 1024;   // [f][sb][tr][dd]
  const _Float16* vbase = vTn + (size_t)bh * 32 * 2048;  // [kb][d][tk]
  const int fragoff = lr * 16 + g * 4;
  const int nf = wave & 3, kh = wave >> 2;

  for (int t = 0; t < 2; ++t) {
    const int rt = pair * 2 + t;
    const int r0 = rt << 4;
    const int fq = (b * NTOK + r0) >> 4;
    const size_t gbase = ((size_t)bh * 64 + rt) * 16384;

    // prefetch attn_last directly into C-register positions (coalesced)
    half4 prev4[8];
    if (has_prev) {
#pragma unroll
      for (int fl = 0; fl < 8; ++fl)
        prev4[fl] = *(const half4*)(store + gbase +
                                    (size_t)(wave * 8 + fl) * 256 + fragoff);
    }

    const half8 a0 = *(const half8*)(
        qF + (((size_t)fq * 16 + h * 2) * 16 + lr) * 32 + g * 8);
    const half8 a1 = *(const half8*)(
        qF + (((size_t)fq * 16 + h * 2 + 1) * 16 + lr) * 32 + g * 8);

    // ---- QK^T + exp + partial row sums ----
    float p[8][4];
    float rs[4] = {0.f, 0.f, 0.f, 0.f};
    __builtin_amdgcn_s_setprio(1);
#pragma unroll
    for (int fl = 0; fl < 8; ++fl) {
      const int f = wave * 8 + fl;
      const _Float16* kb = kbase + (size_t)f * 1024 + lr * 32 + g * 8;
      half8 b0 = *(const half8*)(kb);
      half8 b1 = *(const half8*)(kb + 512);
      f32x4 acc = {0.f, 0.f, 0.f, 0.f};
      acc = __builtin_amdgcn_mfma_f32_16x16x32_f16(a0, b0, acc, 0, 0, 0);
      acc = __builtin_amdgcn_mfma_f32_16x16x32_f16(a1, b1, acc, 0, 0, 0);
#pragma unroll
      for (int j = 0; j < 4; ++j) {
        float e = __expf(acc[j] * 0.125f);
        p[fl][j] = e;
        rs[j] += e;
      }
    }
    __builtin_amdgcn_s_setprio(0);
#pragma unroll
    for (int j = 0; j < 4; ++j) {
      rs[j] += __shfl_xor(rs[j], 1);
      rs[j] += __shfl_xor(rs[j], 2);
      rs[j] += __shfl_xor(rs[j], 4);
      rs[j] += __shfl_xor(rs[j], 8);
    }
    if (lr == 0) {
#pragma unroll
      for (int j = 0; j < 4; ++j) partial[wave][g * 4 + j] = rs[j];
    }
    __syncthreads();  // barrier 1

    f32x4 sv = {0.f, 0.f, 0.f, 0.f};
#pragma unroll
    for (int w = 0; w < 8; ++w) {
      const float4 pw = *(const float4*)&partial[w][g * 4];
      sv[0] += pw.x; sv[1] += pw.y; sv[2] += pw.z; sv[3] += pw.w;
    }
    float inv[4];
#pragma unroll
    for (int j = 0; j < 4; ++j) inv[j] = 1.0f / sv[j];

    // normalize + add prev IN REGISTERS; scatter to P; keep half4 for store
    half4 t4[8];
#pragma unroll
    for (int fl = 0; fl < 8; ++fl) {
      const int c = wave * 128 + fl * 16 + lr;
#pragma unroll
      for (int j = 0; j < 4; ++j) {
        float val = p[fl][j] * inv[j];
        if (has_prev) val += (float)prev4[fl][j];
        const _Float16 hv = (_Float16)val;
        t4[fl][j] = hv;
        P[pidx(g * 4 + j, c)] = hv;
      }
    }
    __syncthreads();  // barrier 2: P ready

    // ---- PV ----
    f32x4 oacc = {0.f, 0.f, 0.f, 0.f};
    __builtin_amdgcn_s_setprio(1);
#pragma unroll
    for (int ks = 0; ks < 16; ++ks) {
      const int kb = kh * 16 + ks;
      half8 af = *(half8*)(P + pidx(lr, kb * 32 + g * 8));
      half8 bfv =
          *(const half8*)(vbase + ((size_t)kb * 64 + nf * 16 + lr) * 32 + g * 8);
      oacc = __builtin_amdgcn_mfma_f32_16x16x32_f16(af, bfv, oacc, 0, 0, 0);
    }
    __builtin_amdgcn_s_setprio(0);
    __syncthreads();  // barrier 3: all waves done reading P

    if (write_store) {
#pragma unroll
      for (int fl = 0; fl < 8; ++fl)
        *(half4*)(store + gbase + (size_t)(wave * 8 + fl) * 256 + fragoff) =
            t4[fl];
    }

#pragma unroll
    for (int j = 0; j < 4; ++j) red[kh][g * 4 + j][nf * 16 + lr] = oacc[j];
    __syncthreads();  // barrier 4
#pragma unroll
    for (int it = 0; it < 2; ++it) {
      const int e = tid + it * 512;
      const int r = e >> 6, d = e & 63;
      float s = red[0][r][d] + red[1][r][d];
      aoutF[(((size_t)fq * 16 + h * 2 + (d >> 5)) * 16 + r) * 32 + (d & 31)] =
          (_Float16)s;
    }
    // next tile's P scatter happens after its own barrier 1 -> no hazard
  }
}

// ---------------------------------------------------------------------------
// Depthwise 3x3 conv (SAME) + bias + exact-erf GELU. fp16 in (row-major),
// fp16 out in F-layout (rows x 96, KS=3). grid 768.
// ---------------------------------------------------------------------------
__global__ __launch_bounds__(256) void dwconv_gelu(const _Float16* __restrict__ y,
                                                   const float* __restrict__ w,
                                                   const float* __restrict__ bs,
                                                   _Float16* __restrict__ outF) {
  const int blk = blockIdx.x;
  const int bb = blk / 96;
  const int rem = blk - bb * 96;
  const int hh = rem / 3, cg = rem - (rem / 3) * 3;
#pragma unroll
  for (int it = 0; it < 4; ++it) {
    const int e = threadIdx.x + it * 256;
    const int c = cg * 32 + (e & 31), ww = e >> 5;
    float acc = bs[c];
#pragma unroll
    for (int dh = 0; dh < 3; ++dh) {
      int ih = hh + dh - 1;
      if (ih < 0 || ih >= 32) continue;
#pragma unroll
      for (int dw = 0; dw < 3; ++dw) {
        int iw = ww + dw - 1;
        if (iw < 0 || iw >= 32) continue;
        acc += (float)y[((size_t)(bb * NTOK + ih * 32 + iw)) * HID + c] *
               w[c * 9 + dh * 3 + dw];
      }
    }
    float gl = 0.5f * acc * (1.f + erff(acc * 0.70710678118f));
    const int f = bb * 64 + hh * 2 + (ww >> 4);
    outF[(((size_t)f * 3 + cg) * 16 + (ww & 15)) * 32 + (e & 31)] = (_Float16)gl;
  }
}

// ---------------------------------------------------------------------------
extern "C" void kernel_launch(void* const* d_in, const int* in_sizes, int n_in,
                              void* d_out, int out_size, void* d_ws,
                              size_t ws_size, hipStream_t stream) {
  const float* x_in  = (const float*)d_in[0];
  const float* ln1_w = (const float*)d_in[1];
  const float* ln1_b = (const float*)d_in[2];
  const float* w_qkv = (const float*)d_in[3];
  const float* w_out = (const float*)d_in[4];
  const float* b_out = (const float*)d_in[5];
  const float* ln2_w = (const float*)d_in[6];
  const float* ln2_b = (const float*)d_in[7];
  const float* fc1_w = (const float*)d_in[8];
  const float* fc1_b = (const float*)d_in[9];
  const float* dw_w  = (const float*)d_in[10];
  const float* dw_b  = (const float*)d_in[11];
  const float* fc2_w = (const float*)d_in[12];
  const float* fc2_b = (const float*)d_in[13];

  float* xout = (float*)d_out;  // final-layer output (fp32) [8192,384]

  char* ws = (char*)d_ws;
  _Float16* x16   = (_Float16*)ws; ws += (size_t)ROWS * DIM * 2;       //  6.3 MB
  _Float16* xnF   = (_Float16*)ws; ws += (size_t)ROWS * DIM * 2;       //  6.3 MB
  _Float16* qF    = (_Float16*)ws; ws += (size_t)ROWS * 512 * 2;       //  8.4 MB
  _Float16* kT    = (_Float16*)ws; ws += (size_t)64 * 64 * 1024 * 2;   //  8.4 MB
  _Float16* vTn   = (_Float16*)ws; ws += (size_t)64 * 32 * 2048 * 2;   //  8.4 MB
  _Float16* aoutF = (_Float16*)ws; ws += (size_t)ROWS * INNER * 2;     //  8.4 MB
  _Float16* y1    = (_Float16*)ws; ws += (size_t)ROWS * HID * 2;       //  1.6 MB
  _Float16* y2F   = (_Float16*)ws; ws += (size_t)ROWS * HID * 2;       //  1.6 MB
  _Float16* wqkvT = (_Float16*)ws; ws += (size_t)DEPTH * 1536 * DIM * 2;
  _Float16* woutT = (_Float16*)ws; ws += (size_t)DEPTH * DIM * INNER * 2;
  _Float16* fc1T  = (_Float16*)ws; ws += (size_t)DEPTH * 128 * DIM * 2;
  _Float16* fc2T  = (_Float16*)ws; ws += (size_t)DEPTH * DIM * HID * 2;
  _Float16* astore = (_Float16*)ws;                                    // 134 MB

  // Weight transpose+convert to F-layout, batched over layers
  transposeW<<<dim3(12, 48, DEPTH), 256, 0, stream>>>(w_qkv, wqkvT, DIM,
                                                      1536, 1536);
  transposeW<<<dim3(16, 12, DEPTH), 256, 0, stream>>>(w_out, woutT, INNER,
                                                      DIM, DIM);
  transposeW<<<dim3(12, 4, DEPTH), 256, 0, stream>>>(fc1_w, fc1T, DIM, HID,
                                                     128);
  transposeW<<<dim3(3, 12, DEPTH), 256, 0, stream>>>(fc2_w, fc2T, HID, DIM,
                                                     DIM);

  // residual stream -> fp16
  cvt_kernel<<<(ROWS * DIM / 4 + 255) / 256, 256, 0, stream>>>(x_in, x16);

  for (int l = 0; l < DEPTH; ++l) {
    // PreNorm + attention
    ln_kernel<<<ROWS / 4, 256, 0, stream>>>(x16, ln1_w + l * DIM,
                                            ln1_b + l * DIM, xnF);
    hgemm_qkv<<<dim3(64, 12), 256, 0, stream>>>(
        xnF, wqkvT + (size_t)l * 1536 * DIM, qF, kT, vTn);
    attn_kernel<<<2048, 512, 0, stream>>>(qF, kT, vTn, astore, aoutF,
                                          l > 0 ? 1 : 0,
                                          l < DEPTH - 1 ? 1 : 0);
    hgemm<true, true, true, INNER, DIM><<<dim3(64, 3), 256, 0, stream>>>(
        aoutF, woutT + (size_t)l * DIM * INNER, b_out + l * DIM, x16, x16);
    // ConvFFN
    ln_kernel<<<ROWS / 4, 256, 0, stream>>>(x16, ln2_w + l * DIM,
                                            ln2_b + l * DIM, xnF);
    hgemm_fc1<<<ROWS / 32, 256, 0, stream>>>(
        xnF, fc1T + (size_t)l * 128 * DIM, fc1_b + l * HID, y1);
    dwconv_gelu<<<768, 256, 0, stream>>>(y1, dw_w + l * HID * 9,
                                         dw_b + l * HID, y2F);
    if (l < DEPTH - 1) {
      hgemm<true, true, true, HID, DIM><<<dim3(64, 3), 256, 0, stream>>>(
          y2F, fc2T + (size_t)l * DIM * HID, fc2_b + l * DIM, x16, x16);
    } else {
      hgemm<true, true, false, HID, DIM><<<dim3(64, 3), 256, 0, stream>>>(
          y2F, fc2T + (size_t)l * DIM * HID, fc2_b + l * DIM, x16, xout);
    }
  }
}

// Round 14
// 649.590 us; speedup vs baseline: 1.3279x; 1.3279x over previous
//
#include <hip/hip_runtime.h>
#include <hip/hip_bf16.h>
#include <math.h>

// Problem constants
#define DEPTH 4
#define DIM 384
#define HEADS 8
#define DHEAD 64
#define INNER 512
#define HID 96
#define BATCH 8
#define NTOK 1024          // 32*32
#define ROWS (BATCH*NTOK)  // 8192

typedef __attribute__((ext_vector_type(8))) _Float16 half8;
typedef __attribute__((ext_vector_type(4))) _Float16 half4;
typedef __attribute__((ext_vector_type(4))) float f32x4;

// F-layout (fragment-native): for a matrix of R rows x K cols (K mult 32,
// R mult 16), elem (r,k) lives at ((r>>4)*KS + (k>>5))*512 + (r&15)*32 + (k&31)
// with KS=K/32. A wave's 16x32 MFMA fragment = 1KB contiguous.

// ---------------------------------------------------------------------------
// LayerNorm over last dim (384) -> fp16 in F-layout. One WAVE per row.
// ---------------------------------------------------------------------------
__global__ __launch_bounds__(256) void ln_kernel(const float* __restrict__ x,
                                                 const float* __restrict__ w,
                                                 const float* __restrict__ b,
                                                 _Float16* __restrict__ outF) {
  const int row = blockIdx.x * 4 + (threadIdx.x >> 6);
  const int lane = threadIdx.x & 63;
  const float* xr = x + (size_t)row * DIM;
  float v[6];
  float s = 0.f;
#pragma unroll
  for (int i = 0; i < 6; ++i) {
    v[i] = xr[lane + i * 64];
    s += v[i];
  }
#pragma unroll
  for (int m = 1; m < 64; m <<= 1) s += __shfl_xor(s, m);
  const float mean = s * (1.0f / DIM);
  float sq = 0.f;
#pragma unroll
  for (int i = 0; i < 6; ++i) {
    v[i] -= mean;
    sq += v[i] * v[i];
  }
#pragma unroll
  for (int m = 1; m < 64; m <<= 1) sq += __shfl_xor(sq, m);
  const float rs = rsqrtf(sq * (1.0f / DIM) + 1e-5f);
  const int f = row >> 4, lr = row & 15;
#pragma unroll
  for (int i = 0; i < 6; ++i) {
    const int k = lane + i * 64;
    outF[(((size_t)f * 12 + (k >> 5)) * 16 + lr) * 32 + (k & 31)] =
        (_Float16)(v[i] * rs * w[k] + b[k]);
  }
}

// ---------------------------------------------------------------------------
// Weight transpose+convert to F-layout: fp32 [K][N] -> fp16 F over (Npad, K).
// ---------------------------------------------------------------------------
__global__ __launch_bounds__(256) void transposeW(const float* __restrict__ in0,
                                                  _Float16* __restrict__ out0,
                                                  int K, int N, int Npad) {
  __shared__ float t[32][33];
  const int l = blockIdx.z;
  const int KS = K >> 5;
  const float* in = in0 + (size_t)l * K * N;
  _Float16* out = out0 + (size_t)l * Npad * K;
  const int k0 = blockIdx.x * 32, n0 = blockIdx.y * 32;
  const int tx = threadIdx.x & 31, ty = threadIdx.x >> 5;
#pragma unroll
  for (int i = 0; i < 4; ++i) {
    int k = k0 + ty + i * 8, n = n0 + tx;
    t[ty + i * 8][tx] = (n < N) ? in[(size_t)k * N + n] : 0.f;
  }
  __syncthreads();
  const int k = k0 + tx;
#pragma unroll
  for (int i = 0; i < 4; ++i) {
    int n = n0 + ty + i * 8;
    if (n < Npad)
      out[(((size_t)(n >> 4) * KS + (k >> 5)) * 16 + (n & 15)) * 32 + (k & 31)] =
          (_Float16)t[tx][ty + i * 8];
  }
}

// ---------------------------------------------------------------------------
// fp16 MFMA GEMM, F-layout A and B: C[M][N] = A @ B^T (+bias, +res).
// 128x128 tile, 4 waves (2x2), 64x64/wave. All frag loads 1KB coalesced.
// ---------------------------------------------------------------------------
template <bool BIAS, bool RES, bool OUT16, int KT, int NT>
__global__ __launch_bounds__(256) void hgemm(const _Float16* __restrict__ AF,
                                             const _Float16* __restrict__ BF,
                                             const float* __restrict__ bias,
                                             const float* __restrict__ res,
                                             void* __restrict__ Cout) {
  constexpr int KS = KT / 32;
  const int tid = threadIdx.x;
  const int wave = tid >> 6, lane = tid & 63;
  const int wm = wave >> 1, wn = wave & 1;
  const int g = lane >> 4, lr = lane & 15;
  const int m0 = blockIdx.x * 128 + wm * 64;
  const int n0 = blockIdx.y * 128 + wn * 64;
  const int fA = m0 >> 4, fB = n0 >> 4;
  const int lo = lr * 32 + g * 8;
  f32x4 acc[4][4];
#pragma unroll
  for (int i = 0; i < 4; ++i)
#pragma unroll
    for (int j = 0; j < 4; ++j) acc[i][j] = {0.f, 0.f, 0.f, 0.f};

  for (int ks = 0; ks < KS; ++ks) {
    half8 af[4], bf[4];
#pragma unroll
    for (int i = 0; i < 4; ++i)
      af[i] = *(const half8*)(AF + ((size_t)(fA + i) * KS + ks) * 512 + lo);
#pragma unroll
    for (int j = 0; j < 4; ++j)
      bf[j] = *(const half8*)(BF + ((size_t)(fB + j) * KS + ks) * 512 + lo);
#pragma unroll
    for (int i = 0; i < 4; ++i)
#pragma unroll
      for (int j = 0; j < 4; ++j)
        acc[i][j] =
            __builtin_amdgcn_mfma_f32_16x16x32_f16(af[i], bf[j], acc[i][j], 0, 0, 0);
  }

#pragma unroll
  for (int i = 0; i < 4; ++i) {
#pragma unroll
    for (int j = 0; j < 4; ++j) {
      const int n = n0 + j * 16 + lr;
      if (NT % 128 == 0 || n < NT) {
        float bb = BIAS ? bias[n] : 0.f;
#pragma unroll
        for (int jj = 0; jj < 4; ++jj) {
          const int m = m0 + i * 16 + g * 4 + jj;
          float v = acc[i][j][jj] + bb;
          const size_t idx = (size_t)m * NT + n;
          if (RES) v += res[idx];
          if (OUT16)
            ((_Float16*)Cout)[idx] = (_Float16)v;
          else
            ((float*)Cout)[idx] = v;
        }
      }
    }
  }
}

// ---------------------------------------------------------------------------
// fc1 GEMM: 32x128 tile, F-layout A (xnF) and B; C fp16 row-major [8192][96].
// grid ROWS/32 = 256.
// ---------------------------------------------------------------------------
__global__ __launch_bounds__(256) void hgemm_fc1(const _Float16* __restrict__ AF,
                                                 const _Float16* __restrict__ BF,
                                                 const float* __restrict__ bias,
                                                 _Float16* __restrict__ C) {
  const int tid = threadIdx.x;
  const int wave = tid >> 6, lane = tid & 63;
  const int g = lane >> 4, lr = lane & 15;
  const int m0 = blockIdx.x * 32;
  const int fA = m0 >> 4, fB = wave * 2;
  const int lo = lr * 32 + g * 8;
  f32x4 acc[2][2];
#pragma unroll
  for (int i = 0; i < 2; ++i)
#pragma unroll
    for (int j = 0; j < 2; ++j) acc[i][j] = {0.f, 0.f, 0.f, 0.f};

  for (int ks = 0; ks < 12; ++ks) {
    half8 af[2], bf[2];
#pragma unroll
    for (int i = 0; i < 2; ++i)
      af[i] = *(const half8*)(AF + ((size_t)(fA + i) * 12 + ks) * 512 + lo);
#pragma unroll
    for (int j = 0; j < 2; ++j)
      bf[j] = *(const half8*)(BF + ((size_t)(fB + j) * 12 + ks) * 512 + lo);
#pragma unroll
    for (int i = 0; i < 2; ++i)
#pragma unroll
      for (int j = 0; j < 2; ++j)
        acc[i][j] =
            __builtin_amdgcn_mfma_f32_16x16x32_f16(af[i], bf[j], acc[i][j], 0, 0, 0);
  }

#pragma unroll
  for (int i = 0; i < 2; ++i)
#pragma unroll
    for (int j = 0; j < 2; ++j) {
      const int n = wave * 32 + j * 16 + lr;
      if (n < HID) {
        const float bb = bias[n];
#pragma unroll
        for (int jj = 0; jj < 4; ++jj) {
          const int m = m0 + i * 16 + g * 4 + jj;
          C[(size_t)m * HID + n] = (_Float16)(acc[i][j][jj] + bb);
        }
      }
    }
}

// ---------------------------------------------------------------------------
// qkv GEMM (F-layout A/B). Epilogue emits:
//  Q -> qF (F-layout over rows x 512)
//  K -> kT [bh][f=64][sb=2][tr=16][dd=32]
//  V -> vTn[bh][kb=32][d=64][tk=32]
// ---------------------------------------------------------------------------
__global__ __launch_bounds__(256) void hgemm_qkv(const _Float16* __restrict__ AF,
                                                 const _Float16* __restrict__ BF,
                                                 _Float16* __restrict__ qF,
                                                 _Float16* __restrict__ kT,
                                                 _Float16* __restrict__ vTn) {
  const int tid = threadIdx.x;
  const int wave = tid >> 6, lane = tid & 63;
  const int wm = wave >> 1, wn = wave & 1;
  const int g = lane >> 4, lr = lane & 15;
  const int m0 = blockIdx.x * 128 + wm * 64;
  const int n0 = blockIdx.y * 128 + wn * 64;
  const int fA = m0 >> 4, fB = n0 >> 4;
  const int lo = lr * 32 + g * 8;
  f32x4 acc[4][4];
#pragma unroll
  for (int i = 0; i < 4; ++i)
#pragma unroll
    for (int j = 0; j < 4; ++j) acc[i][j] = {0.f, 0.f, 0.f, 0.f};

  for (int ks = 0; ks < 12; ++ks) {
    half8 af[4], bf[4];
#pragma unroll
    for (int i = 0; i < 4; ++i)
      af[i] = *(const half8*)(AF + ((size_t)(fA + i) * 12 + ks) * 512 + lo);
#pragma unroll
    for (int j = 0; j < 4; ++j)
      bf[j] = *(const half8*)(BF + ((size_t)(fB + j) * 12 + ks) * 512 + lo);
#pragma unroll
    for (int i = 0; i < 4; ++i)
#pragma unroll
      for (int j = 0; j < 4; ++j)
        acc[i][j] =
            __builtin_amdgcn_mfma_f32_16x16x32_f16(af[i], bf[j], acc[i][j], 0, 0, 0);
  }

  if (n0 < 512) {
    // Q -> qF F-layout (rows x 512, KS=16)
#pragma unroll
    for (int i = 0; i < 4; ++i)
#pragma unroll
      for (int j = 0; j < 4; ++j) {
        const int n = n0 + j * 16 + lr;
#pragma unroll
        for (int jj = 0; jj < 4; ++jj) {
          const int m = m0 + i * 16 + g * 4 + jj;
          qF[(((size_t)(m >> 4) * 16 + (n >> 5)) * 16 + (m & 15)) * 32 + (n & 31)] =
              (_Float16)acc[i][j][jj];
        }
      }
  } else if (n0 < 1024) {
#pragma unroll
    for (int j = 0; j < 4; ++j) {
      const int n = n0 + j * 16 + lr;
      const int hk = (n - 512) >> 6, d = (n - 512) & 63;
      const int sb = d >> 5, dd = d & 31;
#pragma unroll
      for (int i = 0; i < 4; ++i)
#pragma unroll
        for (int jj = 0; jj < 4; ++jj) {
          const int m = m0 + i * 16 + g * 4 + jj;
          const int bb = m >> 10, tok = m & 1023;
          const int f = tok >> 4, tr = tok & 15;
          kT[((((size_t)(bb * 8 + hk) * 64 + f) * 2 + sb) * 16 + tr) * 32 + dd] =
              (_Float16)acc[i][j][jj];
        }
    }
  } else {
    const int bb = m0 >> 10;
    const int tok0 = (m0 & 1023) + g * 4;
#pragma unroll
    for (int j = 0; j < 4; ++j) {
      const int dg = n0 + j * 16 + lr - 1024;
      const int hk = dg >> 6, d = dg & 63;
#pragma unroll
      for (int i = 0; i < 4; ++i) {
        const int tok = tok0 + i * 16;
        const int kb = tok >> 5, tk = tok & 31;
        half4 t = {(_Float16)acc[i][j][0], (_Float16)acc[i][j][1],
                   (_Float16)acc[i][j][2], (_Float16)acc[i][j][3]};
        *(half4*)(vTn + (((size_t)(bb * 8 + hk) * 32 + kb) * 64 + d) * 32 + tk) = t;
      }
    }
  }
}

// ---------------------------------------------------------------------------
// MFMA fp16 attention (champion R10 structure): QBLK=16, 512 thr/8 waves,
// 4096 blocks, XCD swizzle, reg-prefetched prev, deferred store, setprio.
// ---------------------------------------------------------------------------
__device__ __forceinline__ int pidx(int r, int c) {
  return ((((r << 11) + (c << 1)) ^ ((r & 15) << 4)) >> 1);
}

__global__ __launch_bounds__(512) void attn_kernel(
    const _Float16* __restrict__ qF, const _Float16* __restrict__ kT,
    const _Float16* __restrict__ vTn, _Float16* __restrict__ store,
    _Float16* __restrict__ aoutF, int has_prev, int write_store) {
  __shared__ __align__(16) char smem[32768];       // P (fp16 16x1024) ...
  _Float16* P = (_Float16*)smem;                   // ... then red aliases it
  float (*red)[16][68] = (float (*)[16][68])smem;  // red[2][16][68] = 8.7 KB
  __shared__ float partial[8][16];
  __shared__ float invs[16];

  const int tid = threadIdx.x;
  const int wave = tid >> 6, lane = tid & 63;
  const int g = lane >> 4, lr = lane & 15;
  const int blk = blockIdx.x;
  const int xcd = blk & 7, j0 = blk >> 3;
  const int bh = xcd * 8 + (j0 >> 6), rt = j0 & 63;
  const int b = bh >> 3, h = bh & 7;
  const int r0 = rt << 4;
  const int fq = (b * NTOK + r0) >> 4;

  const _Float16* kbase = kT + (size_t)bh * 64 * 1024;   // [f][sb][tr][dd]
  const _Float16* vbase = vTn + (size_t)bh * 32 * 2048;  // [kb][d][tk]
  const size_t gbase = ((size_t)bh * NTOK + r0) * 1024;

  // prefetch attn_last (RMW source) into registers — hides under QK^T
  half8 prev[4];
  if (has_prev) {
#pragma unroll
    for (int it = 0; it < 4; ++it) {
      const int e = tid + it * 512;
      const int r = e >> 7, c8 = (e & 127) << 3;
      prev[it] = *(const half8*)(store + gbase + ((size_t)r << 10) + c8);
    }
  }

  // Q fragments from qF (fully coalesced): ks = h*2 (+1)
  const half8 a0 =
      *(const half8*)(qF + (((size_t)fq * 16 + h * 2) * 16 + lr) * 32 + g * 8);
  const half8 a1 = *(const half8*)(
      qF + (((size_t)fq * 16 + h * 2 + 1) * 16 + lr) * 32 + g * 8);

  // ---- QK^T + exp + partial row sums ----
  float p[8][4];
  float rs[4] = {0.f, 0.f, 0.f, 0.f};
  __builtin_amdgcn_s_setprio(1);
#pragma unroll
  for (int fl = 0; fl < 8; ++fl) {
    const int f = wave * 8 + fl;
    const _Float16* kb = kbase + (size_t)f * 1024 + lr * 32 + g * 8;
    half8 b0 = *(const half8*)(kb);
    half8 b1 = *(const half8*)(kb + 512);
    f32x4 acc = {0.f, 0.f, 0.f, 0.f};
    acc = __builtin_amdgcn_mfma_f32_16x16x32_f16(a0, b0, acc, 0, 0, 0);
    acc = __builtin_amdgcn_mfma_f32_16x16x32_f16(a1, b1, acc, 0, 0, 0);
#pragma unroll
    for (int j = 0; j < 4; ++j) {
      float e = __expf(acc[j] * 0.125f);
      p[fl][j] = e;
      rs[j] += e;
    }
  }
  __builtin_amdgcn_s_setprio(0);
#pragma unroll
  for (int j = 0; j < 4; ++j) {
    rs[j] += __shfl_xor(rs[j], 1);
    rs[j] += __shfl_xor(rs[j], 2);
    rs[j] += __shfl_xor(rs[j], 4);
    rs[j] += __shfl_xor(rs[j], 8);
  }
  if (lr == 0) {
#pragma unroll
    for (int j = 0; j < 4; ++j) partial[wave][g * 4 + j] = rs[j];
  }
  __syncthreads();
  if (tid < 16) {
    float s = 0.f;
#pragma unroll
    for (int w = 0; w < 8; ++w) s += partial[w][tid];
    invs[tid] = 1.0f / s;
  }
  __syncthreads();

  // ---- normalize, scatter to swizzled P ----
#pragma unroll
  for (int fl = 0; fl < 8; ++fl) {
    const int c = wave * 128 + fl * 16 + lr;
#pragma unroll
    for (int j = 0; j < 4; ++j) {
      const int r = g * 4 + j;
      P[pidx(r, c)] = (_Float16)(p[fl][j] * invs[r]);
    }
  }
  __syncthreads();

  // ---- P += prev (regs); keep summed value in regs (deferred store) ----
  half8 pvreg[4];
#pragma unroll
  for (int it = 0; it < 4; ++it) {
    const int e = tid + it * 512;
    const int r = e >> 7, c8 = (e & 127) << 3;
    half8 pv = *(half8*)(P + pidx(r, c8));
    if (has_prev) {
#pragma unroll
      for (int k = 0; k < 8; ++k)
        pv[k] = (_Float16)((float)pv[k] + (float)prev[it][k]);
      *(half8*)(P + pidx(r, c8)) = pv;
    }
    pvreg[it] = pv;
  }
  __syncthreads();

  // ---- PV: wave w -> n-frag (w&3), k-half (w>>2) ----
  const int nf = wave & 3, kh = wave >> 2;
  f32x4 oacc = {0.f, 0.f, 0.f, 0.f};
  __builtin_amdgcn_s_setprio(1);
#pragma unroll
  for (int ks = 0; ks < 16; ++ks) {
    const int kb = kh * 16 + ks;
    half8 af = *(half8*)(P + pidx(lr, kb * 32 + g * 8));
    half8 bfv = *(const half8*)(vbase + ((size_t)kb * 64 + nf * 16 + lr) * 32 + g * 8);
    oacc = __builtin_amdgcn_mfma_f32_16x16x32_f16(af, bfv, oacc, 0, 0, 0);
  }
  __builtin_amdgcn_s_setprio(0);
  __syncthreads();  // all waves done reading P before red overlays it

  // deferred running-sum store (fire-and-forget; drains during red phase)
  if (write_store) {
#pragma unroll
    for (int it = 0; it < 4; ++it) {
      const int e = tid + it * 512;
      const int r = e >> 7, c8 = (e & 127) << 3;
      *(half8*)(store + gbase + ((size_t)r << 10) + c8) = pvreg[it];
    }
  }

#pragma unroll
  for (int j = 0; j < 4; ++j) red[kh][g * 4 + j][nf * 16 + lr] = oacc[j];
  __syncthreads();
#pragma unroll
  for (int it = 0; it < 2; ++it) {
    const int e = tid + it * 512;
    const int r = e >> 6, d = e & 63;
    float s = red[0][r][d] + red[1][r][d];
    // aoutF: F-layout over (rows x 512)
    aoutF[(((size_t)fq * 16 + h * 2 + (d >> 5)) * 16 + r) * 32 + (d & 31)] =
        (_Float16)s;
  }
}

// ---------------------------------------------------------------------------
// Depthwise 3x3 conv (SAME) + bias + exact-erf GELU. fp16 in (row-major),
// fp16 out in F-layout (rows x 96, KS=3). grid 768.
// ---------------------------------------------------------------------------
__global__ __launch_bounds__(256) void dwconv_gelu(const _Float16* __restrict__ y,
                                                   const float* __restrict__ w,
                                                   const float* __restrict__ bs,
                                                   _Float16* __restrict__ outF) {
  const int blk = blockIdx.x;
  const int bb = blk / 96;
  const int rem = blk - bb * 96;
  const int hh = rem / 3, cg = rem - (rem / 3) * 3;
#pragma unroll
  for (int it = 0; it < 4; ++it) {
    const int e = threadIdx.x + it * 256;
    const int c = cg * 32 + (e & 31), ww = e >> 5;
    float acc = bs[c];
#pragma unroll
    for (int dh = 0; dh < 3; ++dh) {
      int ih = hh + dh - 1;
      if (ih < 0 || ih >= 32) continue;
#pragma unroll
      for (int dw = 0; dw < 3; ++dw) {
        int iw = ww + dw - 1;
        if (iw < 0 || iw >= 32) continue;
        acc += (float)y[((size_t)(bb * NTOK + ih * 32 + iw)) * HID + c] *
               w[c * 9 + dh * 3 + dw];
      }
    }
    float gl = 0.5f * acc * (1.f + erff(acc * 0.70710678118f));
    const int f = bb * 64 + hh * 2 + (ww >> 4);
    outF[(((size_t)f * 3 + cg) * 16 + (ww & 15)) * 32 + (e & 31)] = (_Float16)gl;
  }
}

// ---------------------------------------------------------------------------
extern "C" void kernel_launch(void* const* d_in, const int* in_sizes, int n_in,
                              void* d_out, int out_size, void* d_ws,
                              size_t ws_size, hipStream_t stream) {
  const float* x_in  = (const float*)d_in[0];
  const float* ln1_w = (const float*)d_in[1];
  const float* ln1_b = (const float*)d_in[2];
  const float* w_qkv = (const float*)d_in[3];
  const float* w_out = (const float*)d_in[4];
  const float* b_out = (const float*)d_in[5];
  const float* ln2_w = (const float*)d_in[6];
  const float* ln2_b = (const float*)d_in[7];
  const float* fc1_w = (const float*)d_in[8];
  const float* fc1_b = (const float*)d_in[9];
  const float* dw_w  = (const float*)d_in[10];
  const float* dw_b  = (const float*)d_in[11];
  const float* fc2_w = (const float*)d_in[12];
  const float* fc2_b = (const float*)d_in[13];

  float* x = (float*)d_out;  // residual stream lives in d_out [8192,384] fp32

  char* ws = (char*)d_ws;
  _Float16* xnF   = (_Float16*)ws; ws += (size_t)ROWS * DIM * 2;       //  6.3 MB
  _Float16* qF    = (_Float16*)ws; ws += (size_t)ROWS * 512 * 2;       //  8.4 MB
  _Float16* kT    = (_Float16*)ws; ws += (size_t)64 * 64 * 1024 * 2;   //  8.4 MB
  _Float16* vTn   = (_Float16*)ws; ws += (size_t)64 * 32 * 2048 * 2;   //  8.4 MB
  _Float16* aoutF = (_Float16*)ws; ws += (size_t)ROWS * INNER * 2;     //  8.4 MB
  _Float16* y1    = (_Float16*)ws; ws += (size_t)ROWS * HID * 2;       //  1.6 MB
  _Float16* y2F   = (_Float16*)ws; ws += (size_t)ROWS * HID * 2;       //  1.6 MB
  _Float16* wqkvT = (_Float16*)ws; ws += (size_t)DEPTH * 1536 * DIM * 2;
  _Float16* woutT = (_Float16*)ws; ws += (size_t)DEPTH * DIM * INNER * 2;
  _Float16* fc1T  = (_Float16*)ws; ws += (size_t)DEPTH * 128 * DIM * 2;
  _Float16* fc2T  = (_Float16*)ws; ws += (size_t)DEPTH * DIM * HID * 2;
  _Float16* astore = (_Float16*)ws;                                    // 134 MB

  // Weight transpose+convert to F-layout, batched over layers
  transposeW<<<dim3(12, 48, DEPTH), 256, 0, stream>>>(w_qkv, wqkvT, DIM,
                                                      1536, 1536);
  transposeW<<<dim3(16, 12, DEPTH), 256, 0, stream>>>(w_out, woutT, INNER,
                                                      DIM, DIM);
  transposeW<<<dim3(12, 4, DEPTH), 256, 0, stream>>>(fc1_w, fc1T, DIM, HID,
                                                     128);
  transposeW<<<dim3(3, 12, DEPTH), 256, 0, stream>>>(fc2_w, fc2T, HID, DIM,
                                                     DIM);

  hipMemcpyAsync(x, x_in, (size_t)ROWS * DIM * 4, hipMemcpyDeviceToDevice,
                 stream);

  for (int l = 0; l < DEPTH; ++l) {
    // PreNorm + attention
    ln_kernel<<<ROWS / 4, 256, 0, stream>>>(x, ln1_w + l * DIM,
                                            ln1_b + l * DIM, xnF);
    hgemm_qkv<<<dim3(64, 12), 256, 0, stream>>>(
        xnF, wqkvT + (size_t)l * 1536 * DIM, qF, kT, vTn);
    attn_kernel<<<4096, 512, 0, stream>>>(qF, kT, vTn, astore, aoutF,
                                          l > 0 ? 1 : 0,
                                          l < DEPTH - 1 ? 1 : 0);
    hgemm<true, true, false, INNER, DIM><<<dim3(64, 3), 256, 0, stream>>>(
        aoutF, woutT + (size_t)l * DIM * INNER, b_out + l * DIM, x, x);
    // ConvFFN
    ln_kernel<<<ROWS / 4, 256, 0, stream>>>(x, ln2_w + l * DIM,
                                            ln2_b + l * DIM, xnF);
    hgemm_fc1<<<ROWS / 32, 256, 0, stream>>>(
        xnF, fc1T + (size_t)l * 128 * DIM, fc1_b + l * HID, y1);
    dwconv_gelu<<<768, 256, 0, stream>>>(y1, dw_w + l * HID * 9,
                                         dw_b + l * HID, y2F);
    hgemm<true, true, false, HID, DIM><<<dim3(64, 3), 256, 0, stream>>>(
        y2F, fc2T + (size_t)l * DIM * HID, fc2_b + l * DIM, x, x);
  }
}